// Round 10
// baseline (264.837 us; speedup 1.0000x reference)
//
#include <hip/hip_runtime.h>
#include <cstdint>

// ---------------------------------------------------------------------------
// Qwen2 attention block, MI355X/gfx950. Round 9: v10 —
// attn: v9 structure (2 q-subtiles/wave) with P-LDS halved to 8KB
//       (sequential-subtile PV) -> 72KB LDS -> 2 blocks/CU = 8 waves.
// QKV GEMM: bias+RoPE+scatter+V-transpose fused into the epilogue
//       (wave col-fragments remapped so RoPE pairs (d,d+64) are in-wave);
//       rope_kernel / vtrans_kernel / concat_bias deleted.
// ---------------------------------------------------------------------------

typedef short bf16x8 __attribute__((ext_vector_type(8)));
typedef float f32x4 __attribute__((ext_vector_type(4)));

static constexpr int Bsz = 2, Ssz = 2048, Hsz = 2048;
static constexpr int NH = 16, NKV = 4, HD = 128;
static constexpr int Mrows = Bsz * Ssz;              // 4096
static constexpr int NQKV = (NH + 2 * NKV) * HD;     // 3072
static constexpr float SC2 = 0.08838834764831845f * 1.4426950408889634f; // HD^-.5 * log2(e)

__device__ __forceinline__ unsigned short f2bf(float f) {
  union { float f; unsigned u; } x; x.f = f;
  unsigned r = x.u + 0x7fffu + ((x.u >> 16) & 1u);   // RNE
  return (unsigned short)(r >> 16);
}
__device__ __forceinline__ float b2f(unsigned short h) {
  union { unsigned u; float f; } x; x.u = ((unsigned)h) << 16;
  return x.f;
}
__device__ __forceinline__ unsigned cvt_pk_bf16(float lo, float hi) {
  unsigned r;
  asm("v_cvt_pk_bf16_f32 %0, %1, %2" : "=v"(r) : "v"(lo), "v"(hi));
  return r;
}

// async global->LDS, 16B per lane. lds dest must be wave-uniform; HW adds lane*16.
__device__ __forceinline__ void gload_lds16(const void* g, void* lds) {
  auto gp = reinterpret_cast<const __attribute__((address_space(1))) unsigned int*>(
      reinterpret_cast<uintptr_t>(g));
  auto lp = reinterpret_cast<__attribute__((address_space(3))) unsigned int*>(
      static_cast<uint32_t>(reinterpret_cast<uintptr_t>(lds)));
  __builtin_amdgcn_global_load_lds(gp, lp, 16, 0, 0);
}

// ---------------------------------------------------------------------------
__global__ __launch_bounds__(256) void cast_f32_bf16(
    const float* __restrict__ in, unsigned short* __restrict__ out, int n) {
  int i = (blockIdx.x * 256 + threadIdx.x) * 4;
  if (i < n) {
    float4 v = *(const float4*)(in + i);
    ushort4 o;
    o.x = f2bf(v.x); o.y = f2bf(v.y); o.z = f2bf(v.z); o.w = f2bf(v.w);
    *(ushort4*)(out + i) = o;
  }
}

// ---------------------------------------------------------------------------
// Generic C[M][N] = A[M][K] * B[N][K]^T. 128x128 tile, BK=32, 4 waves (2x2).
template <typename OutT>
__global__ __launch_bounds__(256) void gemm_bt(
    const unsigned short* __restrict__ A, const unsigned short* __restrict__ Bm,
    OutT* __restrict__ C, int K, int N) {
  __shared__ unsigned short As[128 * 32];
  __shared__ unsigned short Bs[128 * 32];
  const int t = threadIdx.x;
  const int lane = t & 63;
  const int l16 = lane & 15, lg = lane >> 4;
  const int w = t >> 6;
  const int wm = (w >> 1) * 64, wn = (w & 1) * 64;
  const int tm = blockIdx.x * 128, tn = blockIdx.y * 128;

  f32x4 acc[4][4] = {};

  for (int k0 = 0; k0 < K; k0 += 32) {
#pragma unroll
    for (int i = 0; i < 2; ++i) {
      int c = i * 256 + t;
      const unsigned short* ga = A + (size_t)(tm + (c >> 2)) * K + k0 + (c & 3) * 8;
      const unsigned short* gb = Bm + (size_t)(tn + (c >> 2)) * K + k0 + (c & 3) * 8;
      gload_lds16(ga, (char*)As + (((c >> 6)) << 10));
      gload_lds16(gb, (char*)Bs + (((c >> 6)) << 10));
    }
    __syncthreads();
    bf16x8 af[4], bfr[4];
#pragma unroll
    for (int m = 0; m < 4; ++m)
      af[m] = *(const bf16x8*)(As + (wm + m * 16 + l16) * 32 + lg * 8);
#pragma unroll
    for (int n = 0; n < 4; ++n)
      bfr[n] = *(const bf16x8*)(Bs + (wn + n * 16 + l16) * 32 + lg * 8);
#pragma unroll
    for (int m = 0; m < 4; ++m)
#pragma unroll
      for (int n = 0; n < 4; ++n)
        acc[m][n] = __builtin_amdgcn_mfma_f32_16x16x32_bf16(af[m], bfr[n], acc[m][n], 0, 0, 0);
    __syncthreads();
  }

#pragma unroll
  for (int m = 0; m < 4; ++m)
#pragma unroll
    for (int n = 0; n < 4; ++n) {
      int col = tn + wn + n * 16 + l16;
#pragma unroll
      for (int r = 0; r < 4; ++r) {
        int row = tm + wm + m * 16 + lg * 4 + r;
        C[(size_t)row * N + col] = (OutT)(acc[m][n][r]);
      }
    }
}

// ---------------------------------------------------------------------------
// Fused QKV GEMM: C = X * Wqkv^T, epilogue applies bias + RoPE (Q pre-scaled
// by SC2) and scatters into Qr [B][NH][S][HD], Kr [B][NKV][S][HD],
// Vt [B][NKV][HD][S]. BN=128 = exactly one head. Wave col-fragments remapped
// to {wn, wn+16, wn+64, wn+80} (wn = (w&1)*32) so the RoPE pair (d, d+64)
// is acc[m][n] / acc[m][n+2] within the same wave.
__global__ __launch_bounds__(256) void gemm_qkv(
    const unsigned short* __restrict__ A, const unsigned short* __restrict__ Bm,
    const float* __restrict__ qb, const float* __restrict__ kb,
    const float* __restrict__ vb, const float* __restrict__ cosp,
    const float* __restrict__ sinp, unsigned short* __restrict__ Qr,
    unsigned short* __restrict__ Kr, unsigned short* __restrict__ Vt) {
  __shared__ unsigned short As[128 * 32];
  __shared__ unsigned short Bs[128 * 32];
  const int t = threadIdx.x;
  const int lane = t & 63;
  const int l16 = lane & 15, lg = lane >> 4;
  const int w = t >> 6;
  const int wm = (w >> 1) * 64, wn = (w & 1) * 32;   // note: 32, not 64
  const int tm = blockIdx.x * 128, tn = blockIdx.y * 128;
  const int K = Hsz;

  f32x4 acc[4][4] = {};

  for (int k0 = 0; k0 < K; k0 += 32) {
#pragma unroll
    for (int i = 0; i < 2; ++i) {
      int c = i * 256 + t;
      const unsigned short* ga = A + (size_t)(tm + (c >> 2)) * K + k0 + (c & 3) * 8;
      const unsigned short* gb = Bm + (size_t)(tn + (c >> 2)) * K + k0 + (c & 3) * 8;
      gload_lds16(ga, (char*)As + (((c >> 6)) << 10));
      gload_lds16(gb, (char*)Bs + (((c >> 6)) << 10));
    }
    __syncthreads();
    bf16x8 af[4], bfr[4];
#pragma unroll
    for (int m = 0; m < 4; ++m)
      af[m] = *(const bf16x8*)(As + (wm + m * 16 + l16) * 32 + lg * 8);
#pragma unroll
    for (int n = 0; n < 4; ++n) {
      int coln = wn + (n & 1) * 16 + (n >> 1) * 64;  // remapped fragment col
      bfr[n] = *(const bf16x8*)(Bs + (coln + l16) * 32 + lg * 8);
    }
#pragma unroll
    for (int m = 0; m < 4; ++m)
#pragma unroll
      for (int n = 0; n < 4; ++n)
        acc[m][n] = __builtin_amdgcn_mfma_f32_16x16x32_bf16(af[m], bfr[n], acc[m][n], 0, 0, 0);
    __syncthreads();
  }

  // ---- fused epilogue: bias + RoPE + scatter
  const int region = (tn < 2048) ? 0 : (tn < 2560 ? 1 : 2);
#pragma unroll
  for (int n = 0; n < 2; ++n) {
    const int dl = wn + n * 16 + l16;                // 0..63 (pair: dl, dl+64)
    float b1, b2;
    if (region == 0)      { b1 = qb[tn + dl]; b2 = qb[tn + dl + 64]; }
    else if (region == 1) { b1 = kb[tn - 2048 + dl]; b2 = kb[tn - 2048 + dl + 64]; }
    else                  { b1 = vb[tn - 2560 + dl]; b2 = vb[tn - 2560 + dl + 64]; }
#pragma unroll
    for (int m = 0; m < 4; ++m) {
#pragma unroll
      for (int r = 0; r < 4; ++r) {
        const int row = tm + wm + m * 16 + lg * 4 + r;
        const int s = row & 2047, bb = row >> 11;
        float x1 = acc[m][n][r] + b1;
        float x2 = acc[m][n + 2][r] + b2;
        if (region == 2) {
          const int g = (tn - 2560) >> 7;
          size_t o = ((size_t)(bb * NKV + g) * HD + dl) * (size_t)Ssz + s;
          Vt[o] = f2bf(x1);
          Vt[o + (size_t)64 * Ssz] = f2bf(x2);
        } else {
          // cos/sin: cos[d] == cos[d+64] by construction
          const float c = cosp[(size_t)row * HD + dl];
          const float sn = sinp[(size_t)row * HD + dl];
          if (region == 0) {
            const int h = tn >> 7;
            size_t o = ((size_t)(bb * NH + h) * Ssz + s) * HD + dl;
            Qr[o] = f2bf((x1 * c - x2 * sn) * SC2);
            Qr[o + 64] = f2bf((x2 * c + x1 * sn) * SC2);
          } else {
            const int g = (tn - 2048) >> 7;
            size_t o = ((size_t)(bb * NKV + g) * Ssz + s) * HD + dl;
            Kr[o] = f2bf(x1 * c - x2 * sn);
            Kr[o + 64] = f2bf(x2 * c + x1 * sn);
          }
        }
      }
    }
  }
}

// ---------------------------------------------------------------------------
// Flash causal GQA attention, v10: 4-wave block, 32 q-rows/wave (2 sub-tiles),
// shared dbuf K/V staging, P-LDS 8KB with sequential-subtile PV.
// Grid: 512 blocks x 256 threads, id = kvg + 8*(hr + 4*(15-qt)); kvg pins KV
// group to one XCD. KBLK=64. Swapped QK^T, static-max exp2 softmax.
__global__ __launch_bounds__(256) void attn_kernel(
    const unsigned short* __restrict__ Qr, const unsigned short* __restrict__ Kr,
    const unsigned short* __restrict__ Vt, unsigned short* __restrict__ O) {
  const int id = blockIdx.x;
  const int kvg = id & 7, j = id >> 3;
  const int hr = j & 3;
  const int qt = 15 - (j >> 2);            // 128-row tile; big first
  const int b = kvg >> 2, g = kvg & 3;
  const int h = g * 4 + hr;
  const int t = threadIdx.x;               // 0..255
  const int wave = t >> 6;
  const int lane = t & 63;
  const int l16 = lane & 15, lg = lane >> 4;
  const int qr0 = qt * 128 + wave * 32;    // this wave's 32 q-rows

  const unsigned short* Qh = Qr + (size_t)(b * NH + h) * Ssz * HD;
  const unsigned short* Kh = Kr + (size_t)(b * NKV + g) * Ssz * HD;
  const unsigned short* Vh = Vt + (size_t)(b * NKV + g) * HD * Ssz;

  __shared__ unsigned short Ks[2][64 * 128];   // 32KB, row 256B = 16 slots
  __shared__ unsigned short Vs[2][128 * 64];   // 32KB, row 128B = 8 slots
  __shared__ unsigned short Plds[4][16][64];   // 8KB,  row 128B = 8 slots
  unsigned short(*pw)[64] = Plds[wave];

  // staging source offsets (pre-swizzled: slot ^= row&7 at 16B granularity).
  int koff[4], voff[4];
#pragma unroll
  for (int i = 0; i < 4; ++i) {
    int kr = i * 16 + (t >> 4);              // 0..63, 16 slots/row
    koff[i] = kr * HD + (((t & 15) ^ (kr & 7)) * 8);
    int vr = i * 32 + (t >> 3);              // 0..127, 8 slots/row
    voff[i] = vr * Ssz + (((t & 7) ^ (vr & 7)) * 8);
  }

  auto stage = [&](int buf, int k0) {
#pragma unroll
    for (int i = 0; i < 4; ++i) {
      gload_lds16(Kh + (size_t)k0 * HD + koff[i],
                  (char*)&Ks[buf][0] + i * 4096 + wave * 1024);
      gload_lds16(Vh + k0 + voff[i],
                  (char*)&Vs[buf][0] + i * 4096 + wave * 1024);
    }
  };

  // Q fragments (B operand of swapped MFMA): 2 sub-tiles of 16 rows
  bf16x8 aq[2][4];
#pragma unroll
  for (int qf = 0; qf < 2; ++qf)
#pragma unroll
    for (int c = 0; c < 4; ++c)
      aq[qf][c] = *(const bf16x8*)(Qh + (size_t)(qr0 + qf * 16 + l16) * HD + c * 32 + lg * 8);

  f32x4 acco[8][2] = {};                     // [d-tile][q-subtile]
  float s_l[2] = {0.0f, 0.0f};

  const int nsteps = 2 * qt + 2;
  stage(0, 0);
  int cur = 0;
#pragma unroll 1
  for (int s = 0; s < nsteps; ++s) {
    const int k0 = s * 64;
    if (s + 1 < nsteps) {
      stage(cur ^ 1, k0 + 64);
      asm volatile("s_waitcnt vmcnt(8)" ::: "memory");   // current tile done
    } else {
      asm volatile("s_waitcnt vmcnt(0)" ::: "memory");
    }
    __builtin_amdgcn_s_barrier();            // tile visible block-wide
    __builtin_amdgcn_sched_barrier(0);

    if (k0 <= qr0 + 31) {                    // wave active at this k-step
      // ---- QK^T swapped: sc[kt][qf] = K x Q => C[k][q], q = l16
      f32x4 sc[4][2] = {};
      __builtin_amdgcn_s_setprio(1);
#pragma unroll
      for (int kt = 0; kt < 4; ++kt) {
        const int krow = kt * 16 + l16;
#pragma unroll
        for (int c = 0; c < 4; ++c) {
          bf16x8 bk = *(const bf16x8*)((const char*)&Ks[cur][0] + krow * 256 +
                                       (((c * 4 + lg) ^ (krow & 7)) * 16));
          sc[kt][0] = __builtin_amdgcn_mfma_f32_16x16x32_bf16(bk, aq[0][c], sc[kt][0], 0, 0, 0);
          sc[kt][1] = __builtin_amdgcn_mfma_f32_16x16x32_bf16(bk, aq[1][c], sc[kt][1], 0, 0, 0);
        }
      }
      __builtin_amdgcn_s_setprio(0);
      // ---- causal mask (diagonal-overlap steps only)
      if (k0 + 63 > qr0) {
#pragma unroll
        for (int qf = 0; qf < 2; ++qf) {
          int qrow = qr0 + qf * 16 + l16;
#pragma unroll
          for (int kt = 0; kt < 4; ++kt)
#pragma unroll
            for (int r = 0; r < 4; ++r)
              if (k0 + kt * 16 + lg * 4 + r > qrow) sc[kt][qf][r] = -1e30f;
        }
      }
      // ---- static-max softmax + per-subtile pack & PV (P-LDS reused)
#pragma unroll
      for (int qf = 0; qf < 2; ++qf) {
#pragma unroll
        for (int kt = 0; kt < 4; ++kt)
#pragma unroll
          for (int r = 0; r < 4; ++r) sc[kt][qf][r] = exp2f(sc[kt][qf][r]);
        float rs = ((sc[0][qf][0] + sc[0][qf][1]) + (sc[0][qf][2] + sc[0][qf][3])) +
                   ((sc[1][qf][0] + sc[1][qf][1]) + (sc[1][qf][2] + sc[1][qf][3])) +
                   ((sc[2][qf][0] + sc[2][qf][1]) + (sc[2][qf][2] + sc[2][qf][3])) +
                   ((sc[3][qf][0] + sc[3][qf][1]) + (sc[3][qf][2] + sc[3][qf][3]));
        rs += __shfl_xor(rs, 16);
        rs += __shfl_xor(rs, 32);
        s_l[qf] += rs;
        // pack this subtile's P into the wave-private 16-row buffer
#pragma unroll
        for (int kt = 0; kt < 4; ++kt) {
          uint2 pk;
          pk.x = cvt_pk_bf16(sc[kt][qf][0], sc[kt][qf][1]);
          pk.y = cvt_pk_bf16(sc[kt][qf][2], sc[kt][qf][3]);
          *(uint2*)((char*)pw + l16 * 128 +
                    (((kt * 2 + (lg >> 1)) ^ (l16 & 7)) * 16) + (lg & 1) * 8) = pk;
        }
        asm volatile("s_waitcnt lgkmcnt(0)" ::: "memory");
        __builtin_amdgcn_sched_barrier(0);
        // PV for this subtile
        __builtin_amdgcn_s_setprio(1);
#pragma unroll
        for (int kc = 0; kc < 2; ++kc) {
          bf16x8 ap = *(const bf16x8*)((const char*)pw + l16 * 128 +
                                       (((kc * 4 + lg) ^ (l16 & 7)) * 16));
#pragma unroll
          for (int dt = 0; dt < 8; ++dt) {
            const int vrow = dt * 16 + l16;
            bf16x8 bv = *(const bf16x8*)((const char*)&Vs[cur][0] + vrow * 128 +
                                         (((kc * 4 + lg) ^ (vrow & 7)) * 16));
            acco[dt][qf] = __builtin_amdgcn_mfma_f32_16x16x32_bf16(ap, bv, acco[dt][qf], 0, 0, 0);
          }
        }
        __builtin_amdgcn_s_setprio(0);
        asm volatile("s_waitcnt lgkmcnt(0)" ::: "memory");  // reads done before re-pack
        __builtin_amdgcn_sched_barrier(0);
      }
    }
    __builtin_amdgcn_sched_barrier(0);
    __builtin_amdgcn_s_barrier();            // all waves done reading tile
    cur ^= 1;
  }

  // ---- epilogue: O rows q = qr0 + qf*16 + lg*4 + r, cols d = dt*16 + l16
#pragma unroll
  for (int qf = 0; qf < 2; ++qf) {
    float inv[4];
#pragma unroll
    for (int r = 0; r < 4; ++r) inv[r] = 1.0f / __shfl(s_l[qf], lg * 4 + r);
#pragma unroll
    for (int dt = 0; dt < 8; ++dt)
#pragma unroll
      for (int r = 0; r < 4; ++r) {
        int q = qr0 + qf * 16 + lg * 4 + r;
        O[(size_t)(b * Ssz + q) * (NH * HD) + h * HD + dt * 16 + l16] =
            f2bf(acco[dt][qf][r] * inv[r]);
      }
  }
}

// ---------------------------------------------------------------------------
extern "C" void kernel_launch(void* const* d_in, const int* in_sizes, int n_in,
                              void* d_out, int out_size, void* d_ws, size_t ws_size,
                              hipStream_t stream) {
  const float* hs   = (const float*)d_in[0];
  const float* cosp = (const float*)d_in[1];
  const float* sinp = (const float*)d_in[2];
  // d_in[3] attention_mask: pure causal, handled analytically
  const float* q_w = (const float*)d_in[4];
  const float* q_b = (const float*)d_in[5];
  const float* k_w = (const float*)d_in[6];
  const float* k_b = (const float*)d_in[7];
  const float* v_w = (const float*)d_in[8];
  const float* v_b = (const float*)d_in[9];
  const float* o_w = (const float*)d_in[10];
  float* out = (float*)d_out;

  char* p = (char*)d_ws;
  unsigned short* Xb   = (unsigned short*)p; p += (size_t)Mrows * Hsz * 2;
  unsigned short* Wqkv = (unsigned short*)p; p += (size_t)NQKV * Hsz * 2;
  unsigned short* Wo   = (unsigned short*)p; p += (size_t)Hsz * Hsz * 2;
  unsigned short* Qr   = (unsigned short*)p; p += (size_t)Bsz * NH * Ssz * HD * 2;
  unsigned short* Kr   = (unsigned short*)p; p += (size_t)Bsz * NKV * Ssz * HD * 2;
  unsigned short* Vt   = (unsigned short*)p; p += (size_t)Bsz * NKV * HD * Ssz * 2;
  unsigned short* Obuf = (unsigned short*)p; p += (size_t)Mrows * Hsz * 2;

  // casts
  cast_f32_bf16<<<Mrows * Hsz / 1024, 256, 0, stream>>>(hs, Xb, Mrows * Hsz);
  cast_f32_bf16<<<NH * HD * Hsz / 1024, 256, 0, stream>>>(q_w, Wqkv, NH * HD * Hsz);
  cast_f32_bf16<<<NKV * HD * Hsz / 1024, 256, 0, stream>>>(
      k_w, Wqkv + (size_t)NH * HD * Hsz, NKV * HD * Hsz);
  cast_f32_bf16<<<NKV * HD * Hsz / 1024, 256, 0, stream>>>(
      v_w, Wqkv + (size_t)(NH + NKV) * HD * Hsz, NKV * HD * Hsz);
  cast_f32_bf16<<<Hsz * Hsz / 1024, 256, 0, stream>>>(o_w, Wo, Hsz * Hsz);

  // fused QKV projection + bias + RoPE + scatter + V transpose
  gemm_qkv<<<dim3(Mrows / 128, NQKV / 128), 256, 0, stream>>>(
      Xb, Wqkv, q_b, k_b, v_b, cosp, sinp, Qr, Kr, Vt);

  // attention: 512 blocks x 256 threads (2 blocks/CU), XCD-pinned KV groups
  attn_kernel<<<512, 256, 0, stream>>>(Qr, Kr, Vt, Obuf);

  // output projection -> f32
  gemm_bt<float><<<dim3(Mrows / 128, Hsz / 128), 256, 0, stream>>>(
      Obuf, Wo, out, Hsz, Hsz);
}

// Round 11
// 235.564 us; speedup vs baseline: 1.1243x; 1.1243x over previous
//
#include <hip/hip_runtime.h>
#include <cstdint>

// ---------------------------------------------------------------------------
// Qwen2 attention block, MI355X/gfx950. Round 10: v11 —
// QKV GEMM fuses bias+RoPE only, writing ROW-MAJOR QKV with plain coalesced
// stores (v10's head-scatter/V-transpose epilogue removed — it was store-
// bound: 114us, FETCH 68MB). Attention reads Q/K directly from row-major QKV
// (per-lane addressing, stride NQKV); V via small vtrans kernel as before.
// attn: v10 structure (2 q-subtiles/wave, 72KB LDS -> 2 blocks/CU).
// ---------------------------------------------------------------------------

typedef short bf16x8 __attribute__((ext_vector_type(8)));
typedef float f32x4 __attribute__((ext_vector_type(4)));

static constexpr int Bsz = 2, Ssz = 2048, Hsz = 2048;
static constexpr int NH = 16, NKV = 4, HD = 128;
static constexpr int Mrows = Bsz * Ssz;              // 4096
static constexpr int NQKV = (NH + 2 * NKV) * HD;     // 3072
static constexpr float SC2 = 0.08838834764831845f * 1.4426950408889634f; // HD^-.5 * log2(e)

__device__ __forceinline__ unsigned short f2bf(float f) {
  union { float f; unsigned u; } x; x.f = f;
  unsigned r = x.u + 0x7fffu + ((x.u >> 16) & 1u);   // RNE
  return (unsigned short)(r >> 16);
}
__device__ __forceinline__ float b2f(unsigned short h) {
  union { unsigned u; float f; } x; x.u = ((unsigned)h) << 16;
  return x.f;
}
__device__ __forceinline__ unsigned cvt_pk_bf16(float lo, float hi) {
  unsigned r;
  asm("v_cvt_pk_bf16_f32 %0, %1, %2" : "=v"(r) : "v"(lo), "v"(hi));
  return r;
}

// async global->LDS, 16B per lane. lds dest must be wave-uniform; HW adds lane*16.
__device__ __forceinline__ void gload_lds16(const void* g, void* lds) {
  auto gp = reinterpret_cast<const __attribute__((address_space(1))) unsigned int*>(
      reinterpret_cast<uintptr_t>(g));
  auto lp = reinterpret_cast<__attribute__((address_space(3))) unsigned int*>(
      static_cast<uint32_t>(reinterpret_cast<uintptr_t>(lds)));
  __builtin_amdgcn_global_load_lds(gp, lp, 16, 0, 0);
}

// ---------------------------------------------------------------------------
__global__ __launch_bounds__(256) void cast_f32_bf16(
    const float* __restrict__ in, unsigned short* __restrict__ out, int n) {
  int i = (blockIdx.x * 256 + threadIdx.x) * 4;
  if (i < n) {
    float4 v = *(const float4*)(in + i);
    ushort4 o;
    o.x = f2bf(v.x); o.y = f2bf(v.y); o.z = f2bf(v.z); o.w = f2bf(v.w);
    *(ushort4*)(out + i) = o;
  }
}

// ---------------------------------------------------------------------------
// Generic C[M][N] = A[M][K] * B[N][K]^T. 128x128 tile, BK=32, 4 waves (2x2).
template <typename OutT>
__global__ __launch_bounds__(256) void gemm_bt(
    const unsigned short* __restrict__ A, const unsigned short* __restrict__ Bm,
    OutT* __restrict__ C, int K, int N) {
  __shared__ unsigned short As[128 * 32];
  __shared__ unsigned short Bs[128 * 32];
  const int t = threadIdx.x;
  const int lane = t & 63;
  const int l16 = lane & 15, lg = lane >> 4;
  const int w = t >> 6;
  const int wm = (w >> 1) * 64, wn = (w & 1) * 64;
  const int tm = blockIdx.x * 128, tn = blockIdx.y * 128;

  f32x4 acc[4][4] = {};

  for (int k0 = 0; k0 < K; k0 += 32) {
#pragma unroll
    for (int i = 0; i < 2; ++i) {
      int c = i * 256 + t;
      const unsigned short* ga = A + (size_t)(tm + (c >> 2)) * K + k0 + (c & 3) * 8;
      const unsigned short* gb = Bm + (size_t)(tn + (c >> 2)) * K + k0 + (c & 3) * 8;
      gload_lds16(ga, (char*)As + (((c >> 6)) << 10));
      gload_lds16(gb, (char*)Bs + (((c >> 6)) << 10));
    }
    __syncthreads();
    bf16x8 af[4], bfr[4];
#pragma unroll
    for (int m = 0; m < 4; ++m)
      af[m] = *(const bf16x8*)(As + (wm + m * 16 + l16) * 32 + lg * 8);
#pragma unroll
    for (int n = 0; n < 4; ++n)
      bfr[n] = *(const bf16x8*)(Bs + (wn + n * 16 + l16) * 32 + lg * 8);
#pragma unroll
    for (int m = 0; m < 4; ++m)
#pragma unroll
      for (int n = 0; n < 4; ++n)
        acc[m][n] = __builtin_amdgcn_mfma_f32_16x16x32_bf16(af[m], bfr[n], acc[m][n], 0, 0, 0);
    __syncthreads();
  }

#pragma unroll
  for (int m = 0; m < 4; ++m)
#pragma unroll
    for (int n = 0; n < 4; ++n) {
      int col = tn + wn + n * 16 + l16;
#pragma unroll
      for (int r = 0; r < 4; ++r) {
        int row = tm + wm + m * 16 + lg * 4 + r;
        C[(size_t)row * N + col] = (OutT)(acc[m][n][r]);
      }
    }
}

// ---------------------------------------------------------------------------
// Fused QKV GEMM: C = X * Wqkv^T + bias, with RoPE applied in-register to the
// Q and K regions (Q additionally pre-scaled by SC2). Output: ROW-MAJOR
// QKV [4096][3072] bf16 — stores are the plain coalesced GEMM pattern.
// Wave col-fragments remapped to {wn, wn+16, wn+64, wn+80} (wn=(w&1)*32) so
// the RoPE pair (d, d+64) is acc[m][n] / acc[m][n+2] within one thread.
__global__ __launch_bounds__(256) void gemm_qkv(
    const unsigned short* __restrict__ A, const unsigned short* __restrict__ Bm,
    const float* __restrict__ qb, const float* __restrict__ kb,
    const float* __restrict__ vb, const float* __restrict__ cosp,
    const float* __restrict__ sinp, unsigned short* __restrict__ QKV) {
  __shared__ unsigned short As[128 * 32];
  __shared__ unsigned short Bs[128 * 32];
  const int t = threadIdx.x;
  const int lane = t & 63;
  const int l16 = lane & 15, lg = lane >> 4;
  const int w = t >> 6;
  const int wm = (w >> 1) * 64, wn = (w & 1) * 32;   // note: 32, not 64
  const int tm = blockIdx.x * 128, tn = blockIdx.y * 128;
  const int K = Hsz;

  f32x4 acc[4][4] = {};

  for (int k0 = 0; k0 < K; k0 += 32) {
#pragma unroll
    for (int i = 0; i < 2; ++i) {
      int c = i * 256 + t;
      const unsigned short* ga = A + (size_t)(tm + (c >> 2)) * K + k0 + (c & 3) * 8;
      const unsigned short* gb = Bm + (size_t)(tn + (c >> 2)) * K + k0 + (c & 3) * 8;
      gload_lds16(ga, (char*)As + (((c >> 6)) << 10));
      gload_lds16(gb, (char*)Bs + (((c >> 6)) << 10));
    }
    __syncthreads();
    bf16x8 af[4], bfr[4];
#pragma unroll
    for (int m = 0; m < 4; ++m)
      af[m] = *(const bf16x8*)(As + (wm + m * 16 + l16) * 32 + lg * 8);
#pragma unroll
    for (int n = 0; n < 4; ++n) {
      int coln = wn + (n & 1) * 16 + (n >> 1) * 64;  // remapped fragment col
      bfr[n] = *(const bf16x8*)(Bs + (coln + l16) * 32 + lg * 8);
    }
#pragma unroll
    for (int m = 0; m < 4; ++m)
#pragma unroll
      for (int n = 0; n < 4; ++n)
        acc[m][n] = __builtin_amdgcn_mfma_f32_16x16x32_bf16(af[m], bfr[n], acc[m][n], 0, 0, 0);
    __syncthreads();
  }

  // ---- epilogue: bias + RoPE in-register, row-major coalesced stores
  const int region = (tn < 2048) ? 0 : (tn < 2560 ? 1 : 2);
  const float* bias = (region == 0) ? qb + tn
                    : (region == 1) ? kb + (tn - 2048)
                                    : vb + (tn - 2560);
#pragma unroll
  for (int n = 0; n < 2; ++n) {
    const int dl = wn + n * 16 + l16;                // 0..63 (pair: dl, dl+64)
    const float b1 = bias[dl], b2 = bias[dl + 64];
#pragma unroll
    for (int m = 0; m < 4; ++m)
#pragma unroll
      for (int r = 0; r < 4; ++r) {
        const int row = tm + wm + m * 16 + lg * 4 + r;
        float x1 = acc[m][n][r] + b1;
        float x2 = acc[m][n + 2][r] + b2;
        size_t o = (size_t)row * NQKV + tn + dl;
        if (region < 2) {
          const float c = cosp[(size_t)row * HD + dl];   // cos[d]==cos[d+64]
          const float sn = sinp[(size_t)row * HD + dl];
          float y1 = x1 * c - x2 * sn;
          float y2 = x2 * c + x1 * sn;
          if (region == 0) { y1 *= SC2; y2 *= SC2; }
          QKV[o] = f2bf(y1);
          QKV[o + 64] = f2bf(y2);
        } else {
          QKV[o] = f2bf(x1);
          QKV[o + 64] = f2bf(x2);
        }
      }
  }
}

// ---------------------------------------------------------------------------
// V (cols 2560.. of row-major QKV) -> Vt [B][NKV][HD][S]
__global__ __launch_bounds__(256) void vtrans_kernel(
    const unsigned short* __restrict__ QKV, unsigned short* __restrict__ Vt) {
  __shared__ unsigned short tile[32][33];
  int bg = blockIdx.x;             // b*NKV + g
  int s0 = blockIdx.y * 32, d0 = blockIdx.z * 32;
  int b = bg >> 2, g = bg & 3;
  int tx = threadIdx.x & 31, ty = threadIdx.x >> 5;  // 32 x 8
#pragma unroll
  for (int i = 0; i < 4; ++i) {
    int sl = ty + i * 8;
    tile[sl][tx] = QKV[(size_t)(b * Ssz + s0 + sl) * NQKV + (NH + NKV) * HD + g * HD + d0 + tx];
  }
  __syncthreads();
#pragma unroll
  for (int i = 0; i < 4; ++i) {
    int dl = ty + i * 8;
    Vt[((size_t)(b * NKV + g) * HD + d0 + dl) * Ssz + s0 + tx] = tile[tx][dl];
  }
}

// ---------------------------------------------------------------------------
// Flash causal GQA attention, v11: reads Q/K directly from row-major QKV
// (row stride NQKV); otherwise = v10 (4 waves x 32 q-rows, 2 sub-tiles/wave,
// dbuf K/V staging, P-LDS 8KB sequential-subtile PV, 72KB LDS, static-max
// exp2 softmax, big-tile-first grid, XCD-pinned KV groups).
__global__ __launch_bounds__(256) void attn_kernel(
    const unsigned short* __restrict__ QKV, const unsigned short* __restrict__ Vt,
    unsigned short* __restrict__ O) {
  const int id = blockIdx.x;
  const int kvg = id & 7, j = id >> 3;
  const int hr = j & 3;
  const int qt = 15 - (j >> 2);            // 128-row tile; big first
  const int b = kvg >> 2, g = kvg & 3;
  const int h = g * 4 + hr;
  const int t = threadIdx.x;               // 0..255
  const int wave = t >> 6;
  const int lane = t & 63;
  const int l16 = lane & 15, lg = lane >> 4;
  const int qr0 = qt * 128 + wave * 32;    // this wave's 32 q-rows

  const unsigned short* Qh = QKV + (size_t)b * Ssz * NQKV + h * HD;
  const unsigned short* Kh = QKV + (size_t)b * Ssz * NQKV + NH * HD + g * HD;
  const unsigned short* Vh = Vt + (size_t)(b * NKV + g) * HD * Ssz;

  __shared__ unsigned short Ks[2][64 * 128];   // 32KB, row 256B = 16 slots
  __shared__ unsigned short Vs[2][128 * 64];   // 32KB, row 128B = 8 slots
  __shared__ unsigned short Plds[4][16][64];   // 8KB,  row 128B = 8 slots
  unsigned short(*pw)[64] = Plds[wave];

  // staging source offsets (pre-swizzled: slot ^= row&7 at 16B granularity).
  int koff[4], voff[4];
#pragma unroll
  for (int i = 0; i < 4; ++i) {
    int kr = i * 16 + (t >> 4);              // 0..63, 16 slots/row
    koff[i] = kr * NQKV + (((t & 15) ^ (kr & 7)) * 8);
    int vr = i * 32 + (t >> 3);              // 0..127, 8 slots/row
    voff[i] = vr * Ssz + (((t & 7) ^ (vr & 7)) * 8);
  }

  auto stage = [&](int buf, int k0) {
#pragma unroll
    for (int i = 0; i < 4; ++i) {
      gload_lds16(Kh + (size_t)k0 * NQKV + koff[i],
                  (char*)&Ks[buf][0] + i * 4096 + wave * 1024);
      gload_lds16(Vh + k0 + voff[i],
                  (char*)&Vs[buf][0] + i * 4096 + wave * 1024);
    }
  };

  // Q fragments (B operand of swapped MFMA): 2 sub-tiles of 16 rows
  bf16x8 aq[2][4];
#pragma unroll
  for (int qf = 0; qf < 2; ++qf)
#pragma unroll
    for (int c = 0; c < 4; ++c)
      aq[qf][c] = *(const bf16x8*)(Qh + (size_t)(qr0 + qf * 16 + l16) * NQKV + c * 32 + lg * 8);

  f32x4 acco[8][2] = {};                     // [d-tile][q-subtile]
  float s_l[2] = {0.0f, 0.0f};

  const int nsteps = 2 * qt + 2;
  stage(0, 0);
  int cur = 0;
#pragma unroll 1
  for (int s = 0; s < nsteps; ++s) {
    const int k0 = s * 64;
    if (s + 1 < nsteps) {
      stage(cur ^ 1, k0 + 64);
      asm volatile("s_waitcnt vmcnt(8)" ::: "memory");   // current tile done
    } else {
      asm volatile("s_waitcnt vmcnt(0)" ::: "memory");
    }
    __builtin_amdgcn_s_barrier();            // tile visible block-wide
    __builtin_amdgcn_sched_barrier(0);

    if (k0 <= qr0 + 31) {                    // wave active at this k-step
      // ---- QK^T swapped: sc[kt][qf] = K x Q => C[k][q], q = l16
      f32x4 sc[4][2] = {};
      __builtin_amdgcn_s_setprio(1);
#pragma unroll
      for (int kt = 0; kt < 4; ++kt) {
        const int krow = kt * 16 + l16;
#pragma unroll
        for (int c = 0; c < 4; ++c) {
          bf16x8 bk = *(const bf16x8*)((const char*)&Ks[cur][0] + krow * 256 +
                                       (((c * 4 + lg) ^ (krow & 7)) * 16));
          sc[kt][0] = __builtin_amdgcn_mfma_f32_16x16x32_bf16(bk, aq[0][c], sc[kt][0], 0, 0, 0);
          sc[kt][1] = __builtin_amdgcn_mfma_f32_16x16x32_bf16(bk, aq[1][c], sc[kt][1], 0, 0, 0);
        }
      }
      __builtin_amdgcn_s_setprio(0);
      // ---- causal mask (diagonal-overlap steps only)
      if (k0 + 63 > qr0) {
#pragma unroll
        for (int qf = 0; qf < 2; ++qf) {
          int qrow = qr0 + qf * 16 + l16;
#pragma unroll
          for (int kt = 0; kt < 4; ++kt)
#pragma unroll
            for (int r = 0; r < 4; ++r)
              if (k0 + kt * 16 + lg * 4 + r > qrow) sc[kt][qf][r] = -1e30f;
        }
      }
      // ---- static-max softmax + per-subtile pack & PV (P-LDS reused)
#pragma unroll
      for (int qf = 0; qf < 2; ++qf) {
#pragma unroll
        for (int kt = 0; kt < 4; ++kt)
#pragma unroll
          for (int r = 0; r < 4; ++r) sc[kt][qf][r] = exp2f(sc[kt][qf][r]);
        float rs = ((sc[0][qf][0] + sc[0][qf][1]) + (sc[0][qf][2] + sc[0][qf][3])) +
                   ((sc[1][qf][0] + sc[1][qf][1]) + (sc[1][qf][2] + sc[1][qf][3])) +
                   ((sc[2][qf][0] + sc[2][qf][1]) + (sc[2][qf][2] + sc[2][qf][3])) +
                   ((sc[3][qf][0] + sc[3][qf][1]) + (sc[3][qf][2] + sc[3][qf][3]));
        rs += __shfl_xor(rs, 16);
        rs += __shfl_xor(rs, 32);
        s_l[qf] += rs;
        // pack this subtile's P into the wave-private 16-row buffer
#pragma unroll
        for (int kt = 0; kt < 4; ++kt) {
          uint2 pk;
          pk.x = cvt_pk_bf16(sc[kt][qf][0], sc[kt][qf][1]);
          pk.y = cvt_pk_bf16(sc[kt][qf][2], sc[kt][qf][3]);
          *(uint2*)((char*)pw + l16 * 128 +
                    (((kt * 2 + (lg >> 1)) ^ (l16 & 7)) * 16) + (lg & 1) * 8) = pk;
        }
        asm volatile("s_waitcnt lgkmcnt(0)" ::: "memory");
        __builtin_amdgcn_sched_barrier(0);
        // PV for this subtile
        __builtin_amdgcn_s_setprio(1);
#pragma unroll
        for (int kc = 0; kc < 2; ++kc) {
          bf16x8 ap = *(const bf16x8*)((const char*)pw + l16 * 128 +
                                       (((kc * 4 + lg) ^ (l16 & 7)) * 16));
#pragma unroll
          for (int dt = 0; dt < 8; ++dt) {
            const int vrow = dt * 16 + l16;
            bf16x8 bv = *(const bf16x8*)((const char*)&Vs[cur][0] + vrow * 128 +
                                         (((kc * 4 + lg) ^ (vrow & 7)) * 16));
            acco[dt][qf] = __builtin_amdgcn_mfma_f32_16x16x32_bf16(ap, bv, acco[dt][qf], 0, 0, 0);
          }
        }
        __builtin_amdgcn_s_setprio(0);
        asm volatile("s_waitcnt lgkmcnt(0)" ::: "memory");  // reads done before re-pack
        __builtin_amdgcn_sched_barrier(0);
      }
    }
    __builtin_amdgcn_sched_barrier(0);
    __builtin_amdgcn_s_barrier();            // all waves done reading tile
    cur ^= 1;
  }

  // ---- epilogue: O rows q = qr0 + qf*16 + lg*4 + r, cols d = dt*16 + l16
#pragma unroll
  for (int qf = 0; qf < 2; ++qf) {
    float inv[4];
#pragma unroll
    for (int r = 0; r < 4; ++r) inv[r] = 1.0f / __shfl(s_l[qf], lg * 4 + r);
#pragma unroll
    for (int dt = 0; dt < 8; ++dt)
#pragma unroll
      for (int r = 0; r < 4; ++r) {
        int q = qr0 + qf * 16 + lg * 4 + r;
        O[(size_t)(b * Ssz + q) * (NH * HD) + h * HD + dt * 16 + l16] =
            f2bf(acco[dt][qf][r] * inv[r]);
      }
  }
}

// ---------------------------------------------------------------------------
extern "C" void kernel_launch(void* const* d_in, const int* in_sizes, int n_in,
                              void* d_out, int out_size, void* d_ws, size_t ws_size,
                              hipStream_t stream) {
  const float* hs   = (const float*)d_in[0];
  const float* cosp = (const float*)d_in[1];
  const float* sinp = (const float*)d_in[2];
  // d_in[3] attention_mask: pure causal, handled analytically
  const float* q_w = (const float*)d_in[4];
  const float* q_b = (const float*)d_in[5];
  const float* k_w = (const float*)d_in[6];
  const float* k_b = (const float*)d_in[7];
  const float* v_w = (const float*)d_in[8];
  const float* v_b = (const float*)d_in[9];
  const float* o_w = (const float*)d_in[10];
  float* out = (float*)d_out;

  char* p = (char*)d_ws;
  unsigned short* Xb   = (unsigned short*)p; p += (size_t)Mrows * Hsz * 2;
  unsigned short* Wqkv = (unsigned short*)p; p += (size_t)NQKV * Hsz * 2;
  unsigned short* Wo   = (unsigned short*)p; p += (size_t)Hsz * Hsz * 2;
  unsigned short* QKV  = (unsigned short*)p; p += (size_t)Mrows * NQKV * 2;
  unsigned short* Vt   = (unsigned short*)p; p += (size_t)Bsz * NKV * HD * Ssz * 2;
  unsigned short* Obuf = (unsigned short*)p; p += (size_t)Mrows * Hsz * 2;

  // casts
  cast_f32_bf16<<<Mrows * Hsz / 1024, 256, 0, stream>>>(hs, Xb, Mrows * Hsz);
  cast_f32_bf16<<<NH * HD * Hsz / 1024, 256, 0, stream>>>(q_w, Wqkv, NH * HD * Hsz);
  cast_f32_bf16<<<NKV * HD * Hsz / 1024, 256, 0, stream>>>(
      k_w, Wqkv + (size_t)NH * HD * Hsz, NKV * HD * Hsz);
  cast_f32_bf16<<<NKV * HD * Hsz / 1024, 256, 0, stream>>>(
      v_w, Wqkv + (size_t)(NH + NKV) * HD * Hsz, NKV * HD * Hsz);
  cast_f32_bf16<<<Hsz * Hsz / 1024, 256, 0, stream>>>(o_w, Wo, Hsz * Hsz);

  // fused QKV projection + bias + RoPE (row-major coalesced output)
  gemm_qkv<<<dim3(Mrows / 128, NQKV / 128), 256, 0, stream>>>(
      Xb, Wqkv, q_b, k_b, v_b, cosp, sinp, QKV);

  // V transpose (reads QKV V-columns)
  vtrans_kernel<<<dim3(Bsz * NKV, Ssz / 32, HD / 32), 256, 0, stream>>>(QKV, Vt);

  // attention: 512 blocks x 256 threads (2 blocks/CU), XCD-pinned KV groups
  attn_kernel<<<512, 256, 0, stream>>>(QKV, Vt, Obuf);

  // output projection -> f32
  gemm_bt<float><<<dim3(Mrows / 128, Hsz / 128), 256, 0, stream>>>(
      Obuf, Wo, out, Hsz, Hsz);
}